// Round 19
// baseline (116.732 us; speedup 1.0000x reference)
//
#include <hip/hip_runtime.h>
#include <math.h>

#define BATCH 2
#define SEQ 2048
#define BL (BATCH * SEQ)      // 4096
#define EMBED 1024
#define PROJ 512
#define NHEADS 8
#define HDIM 64
#define QKVN (3 * PROJ)       // 1536 fused q|k|v columns
#define KVSPLIT 4
#define KVQ (SEQ / KVSPLIT)   // 512

typedef _Float16 half8 __attribute__((ext_vector_type(8)));
typedef __fp16 fp16x2 __attribute__((ext_vector_type(2)));
typedef float floatx4 __attribute__((ext_vector_type(4)));
typedef float floatx16 __attribute__((ext_vector_type(16)));

// ---------------------------------------------------------------------------
// Fused weight prep: all 5 transposes+converts in one launch.
// ---------------------------------------------------------------------------
__global__ __launch_bounds__(256) void trconv_all(const float* __restrict__ pW,
                                                  const float* __restrict__ Wq,
                                                  const float* __restrict__ Wk,
                                                  const float* __restrict__ Wv,
                                                  const float* __restrict__ oW,
                                                  _Float16* __restrict__ pWt,
                                                  _Float16* __restrict__ qkvWt,
                                                  _Float16* __restrict__ oWt) {
    __shared__ float tile[64][65];
    int id = blockIdx.x;
    const float* src;
    _Float16* dst;
    int K, N;
    float scale = 1.0f;
    if (id < 128)      { src = pW; dst = pWt; K = EMBED; N = PROJ; }
    else if (id < 192) { src = Wq; dst = qkvWt; K = PROJ; N = PROJ;
                         scale = 0.125f * 1.44269504f; id -= 128; }
    else if (id < 256) { src = Wk; dst = qkvWt + (size_t)PROJ * PROJ; K = PROJ; N = PROJ; id -= 192; }
    else if (id < 320) { src = Wv; dst = qkvWt + (size_t)2 * PROJ * PROJ; K = PROJ; N = PROJ; id -= 256; }
    else               { src = oW; dst = oWt; K = PROJ; N = EMBED; id -= 320; }

    const int tn = N / 64;
    const int n0 = (id % tn) * 64;
    const int k0 = (id / tn) * 64;

    const int t  = threadIdx.x;
    const int tx = t & 63;
    const int ty = t >> 6;
#pragma unroll
    for (int i = 0; i < 16; ++i) {
        int k = ty * 16 + i;
        tile[k][tx] = src[(size_t)(k0 + k) * N + n0 + tx];
    }
    __syncthreads();
#pragma unroll
    for (int i = 0; i < 16; ++i) {
        int n = ty * 16 + i;
        dst[(size_t)(n0 + n) * K + k0 + tx] = (_Float16)(tile[tx][n] * scale);
    }
}

// ---------------------------------------------------------------------------
// V pre-transpose: v (f16, rows stride QKVN, head h cols 64) -> vt[b][h][d][SEQ]
// ---------------------------------------------------------------------------
__global__ __launch_bounds__(256) void trans_v(const _Float16* __restrict__ v,
                                               _Float16* __restrict__ vt) {
    __shared__ _Float16 tile[64][72];
    const int t  = threadIdx.x;
    const int t0 = blockIdx.x * 64;
    const int h  = blockIdx.y;
    const int b  = blockIdx.z;
    {
        const int r = t >> 2, c0 = (t & 3) * 16;
        const _Float16* src = v + (size_t)(b * SEQ + t0 + r) * QKVN + h * HDIM + c0;
        *reinterpret_cast<half8*>(&tile[r][c0])     = *reinterpret_cast<const half8*>(src);
        *reinterpret_cast<half8*>(&tile[r][c0 + 8]) = *reinterpret_cast<const half8*>(src + 8);
    }
    __syncthreads();
    {
        const int c = t >> 2, k0 = (t & 3) * 16;
        half8 o1, o2;
#pragma unroll
        for (int i = 0; i < 8; ++i) { o1[i] = tile[k0 + i][c]; o2[i] = tile[k0 + 8 + i][c]; }
        _Float16* dst = vt + ((size_t)(b * NHEADS + h) * HDIM + c) * SEQ + t0 + k0;
        *reinterpret_cast<half8*>(dst)     = o1;
        *reinterpret_cast<half8*>(dst + 8) = o2;
    }
}

// ---------------------------------------------------------------------------
// f16 MFMA GEMM: C[M][N] = A[M][K] @ Bt[N][K]^T (+bias, relu), fp32 accum.
// DOUBLE-BUFFERED LDS, one barrier per K-step.
// ---------------------------------------------------------------------------
template <int BM, int BN, int A_F32, int BIASRELU, int C_F32>
__global__ __launch_bounds__(256) void gemm_mfma(const void* __restrict__ Ap,
                                                 const _Float16* __restrict__ Bt,
                                                 const float* __restrict__ bias,
                                                 void* __restrict__ Cp,
                                                 int M, int N, int K) {
    __shared__ _Float16 Ah[2][BM][40];
    __shared__ _Float16 Bh[2][BN][40];

    constexpr int MF = BM / 32;
    constexpr int NF = BN / 32;
    constexpr int EPA = BM / 8;
    constexpr int TPA = 32 / EPA;
    constexpr int EPB = BN / 8;
    constexpr int TPB = 32 / EPB;

    const int t  = threadIdx.x;
    const int w  = t >> 6;
    const int l  = t & 63;
    const int lr = l & 15;
    const int lg = l >> 4;
    const int bm = blockIdx.y * BM;
    const int bn = blockIdx.x * BN;
    const int wr = w >> 1;
    const int wc = w & 1;

    const int ar = t / TPA, ac = (t % TPA) * EPA;
    const int br = t / TPB, bc = (t % TPB) * EPB;

    floatx4 acc[MF][NF];
#pragma unroll
    for (int i = 0; i < MF; ++i)
#pragma unroll
        for (int j = 0; j < NF; ++j) acc[i][j] = (floatx4){0.f, 0.f, 0.f, 0.f};

    float4 af[EPA / 4];
    half8  ah[EPA / 8];
    half8  bh[EPB / 8];

    const float* Af = (const float*)Ap;
    const _Float16* Ah16 = (const _Float16*)Ap;

    if (A_F32) {
#pragma unroll
        for (int i = 0; i < EPA / 4; ++i)
            af[i] = *reinterpret_cast<const float4*>(&Af[(size_t)(bm + ar) * K + ac + i * 4]);
    } else {
#pragma unroll
        for (int i = 0; i < EPA / 8; ++i)
            ah[i] = *reinterpret_cast<const half8*>(&Ah16[(size_t)(bm + ar) * K + ac + i * 8]);
    }
#pragma unroll
    for (int i = 0; i < EPB / 8; ++i)
        bh[i] = *reinterpret_cast<const half8*>(&Bt[(size_t)(bn + br) * K + bc + i * 8]);

    int pb_ = 0;
    for (int kt = 0; kt < K; kt += 32) {
        if (A_F32) {
#pragma unroll
            for (int i = 0; i < EPA / 8; ++i) {
                half8 hcv;
                float4 a0 = af[2 * i], a1 = af[2 * i + 1];
                hcv[0] = (_Float16)a0.x; hcv[1] = (_Float16)a0.y;
                hcv[2] = (_Float16)a0.z; hcv[3] = (_Float16)a0.w;
                hcv[4] = (_Float16)a1.x; hcv[5] = (_Float16)a1.y;
                hcv[6] = (_Float16)a1.z; hcv[7] = (_Float16)a1.w;
                *reinterpret_cast<half8*>(&Ah[pb_][ar][ac + i * 8]) = hcv;
            }
        } else {
#pragma unroll
            for (int i = 0; i < EPA / 8; ++i)
                *reinterpret_cast<half8*>(&Ah[pb_][ar][ac + i * 8]) = ah[i];
        }
#pragma unroll
        for (int i = 0; i < EPB / 8; ++i)
            *reinterpret_cast<half8*>(&Bh[pb_][br][bc + i * 8]) = bh[i];
        __syncthreads();   // ONE barrier per K-step

        if (kt + 32 < K) {
            if (A_F32) {
#pragma unroll
                for (int i = 0; i < EPA / 4; ++i)
                    af[i] = *reinterpret_cast<const float4*>(&Af[(size_t)(bm + ar) * K + kt + 32 + ac + i * 4]);
            } else {
#pragma unroll
                for (int i = 0; i < EPA / 8; ++i)
                    ah[i] = *reinterpret_cast<const half8*>(&Ah16[(size_t)(bm + ar) * K + kt + 32 + ac + i * 8]);
            }
#pragma unroll
            for (int i = 0; i < EPB / 8; ++i)
                bh[i] = *reinterpret_cast<const half8*>(&Bt[(size_t)(bn + br) * K + kt + 32 + bc + i * 8]);
        }

        half8 afr[MF], bfr[NF];
#pragma unroll
        for (int mf = 0; mf < MF; ++mf)
            afr[mf] = *reinterpret_cast<const half8*>(&Ah[pb_][wr * (BM / 2) + mf * 16 + lr][lg * 8]);
#pragma unroll
        for (int nf = 0; nf < NF; ++nf)
            bfr[nf] = *reinterpret_cast<const half8*>(&Bh[pb_][wc * (BN / 2) + nf * 16 + lr][lg * 8]);
        __builtin_amdgcn_s_setprio(1);
#pragma unroll
        for (int mf = 0; mf < MF; ++mf)
#pragma unroll
            for (int nf = 0; nf < NF; ++nf)
                acc[mf][nf] = __builtin_amdgcn_mfma_f32_16x16x32_f16(afr[mf], bfr[nf], acc[mf][nf], 0, 0, 0);
        __builtin_amdgcn_s_setprio(0);

        pb_ ^= 1;
    }

#pragma unroll
    for (int mf = 0; mf < MF; ++mf)
#pragma unroll
        for (int nf = 0; nf < NF; ++nf) {
            const int n = bn + wc * (BN / 2) + nf * 16 + lr;
            float bs = 0.f;
            if (BIASRELU) bs = bias[n];
#pragma unroll
            for (int r = 0; r < 4; ++r) {
                const int m = bm + wr * (BM / 2) + mf * 16 + lg * 4 + r;
                float v = acc[mf][nf][r];
                if (BIASRELU) v = fmaxf(v + bs, 0.f);
                if (C_F32)
                    ((float*)Cp)[(size_t)m * N + n] = v;
                else
                    ((_Float16*)Cp)[(size_t)m * N + n] = (_Float16)v;
            }
        }
}

// ---------------------------------------------------------------------------
// f16-MFMA flash attention v3.5: v3.4 (T1 XCD swizzle) + MFMA row-sum:
// softmax denominator l = P @ ones rides the matrix pipe (4 extra MFMA/tile)
// instead of 32 VALU adds + shfl; l lands in PV/finalize layout per-lane,
// removing the Fs l-broadcast and finalize barrier.
// ---------------------------------------------------------------------------
__global__ __launch_bounds__(256, 4) void attn_part(const _Float16* __restrict__ Q,
                                                    const _Float16* __restrict__ K,
                                                    const _Float16* __restrict__ Vt,
                                                    _Float16* __restrict__ Op,
                                                    float* __restrict__ ml) {
    __shared__ _Float16 Ks[2][64][64];
    __shared__ _Float16 Vs[2][64][64];
    __shared__ float Fs[4][32];

    const int t  = threadIdx.x;
    const int w  = t >> 6;
    const int l  = t & 63;
    const int ql = l & 31;
    const int hi = l >> 5;

    // ---- T1 chunked XCD swizzle (bijective: 1024 = 8 XCDs x 128) ----
    const int lin     = blockIdx.x;
    const int logical = (lin & 7) * 128 + (lin >> 3);
    const int qt  = logical & 15;
    const int g   = logical >> 4;
    const int kvs = g & 3;
    const int h   = (g >> 2) & 7;
    const int b   = g >> 5;

    const int q0  = qt * 128;
    const size_t base  = (size_t)b * SEQ * QKVN + (size_t)h * HDIM;
    const size_t vbase = (size_t)(b * NHEADS + h) * HDIM * SEQ;
    const size_t poff  = (((size_t)kvs * BATCH + b) * NHEADS + h) * SEQ;

    const int kt0  = kvs * KVQ;
    const int kend = kt0 + KVQ;

    half8 qf[4];
#pragma unroll
    for (int s = 0; s < 4; ++s)
        qf[s] = *reinterpret_cast<const half8*>(
            &Q[base + (size_t)(q0 + w * 32 + ql) * QKVN + s * 16 + hi * 8]);

    // all-ones B fragment: D[q][*] = row-sum of A
    half8 onesf;
#pragma unroll
    for (int i = 0; i < 8; ++i) onesf[i] = (_Float16)1.0f;

    floatx16 o0 = (floatx16)0.f, o1 = (floatx16)0.f;
    floatx16 lacc = (floatx16)0.f;
    float m_s = -1e30f;

    const int rkv  = t >> 2;
    const int c8   = (t & 3) * 2;
    const int swz0 = (c8 ^ (rkv & 7)) * 8;
    const int swz1 = ((c8 + 1) ^ (rkv & 7)) * 8;

    half8 ka0, ka1, va0, va1;
    {
        const _Float16* kp = K + base + (size_t)(kt0 + rkv) * QKVN + c8 * 8;
        ka0 = *reinterpret_cast<const half8*>(kp);
        ka1 = *reinterpret_cast<const half8*>(kp + 8);
        const _Float16* vp = Vt + vbase + (size_t)rkv * SEQ + kt0 + c8 * 8;
        va0 = *reinterpret_cast<const half8*>(vp);
        va1 = *reinterpret_cast<const half8*>(vp + 8);
    }

    int p = 0;
    for (int kt = kt0; kt < kend; kt += 64) {
        *reinterpret_cast<half8*>(&Ks[p][rkv][swz0]) = ka0;
        *reinterpret_cast<half8*>(&Ks[p][rkv][swz1]) = ka1;
        *reinterpret_cast<half8*>(&Vs[p][rkv][swz0]) = va0;
        *reinterpret_cast<half8*>(&Vs[p][rkv][swz1]) = va1;
        __syncthreads();

        if (kt + 64 < kend) {
            const _Float16* kp = K + base + (size_t)(kt + 64 + rkv) * QKVN + c8 * 8;
            ka0 = *reinterpret_cast<const half8*>(kp);
            ka1 = *reinterpret_cast<const half8*>(kp + 8);
            const _Float16* vp = Vt + vbase + (size_t)rkv * SEQ + (kt + 64) + c8 * 8;
            va0 = *reinterpret_cast<const half8*>(vp);
            va1 = *reinterpret_cast<const half8*>(vp + 8);
        }

        // ---- S^T = K @ Q^T (log2 domain) ----
        floatx16 st0 = (floatx16)0.f, st1 = (floatx16)0.f;
        __builtin_amdgcn_s_setprio(1);
#pragma unroll
        for (int s = 0; s < 4; ++s) {
            const int c0 = ((2 * s + hi) ^ (ql & 7)) * 8;
            half8 kf0 = *reinterpret_cast<const half8*>(&Ks[p][ql][c0]);
            half8 kf1 = *reinterpret_cast<const half8*>(&Ks[p][32 + ql][c0]);
            st0 = __builtin_amdgcn_mfma_f32_32x32x16_f16(kf0, qf[s], st0, 0, 0, 0);
            st1 = __builtin_amdgcn_mfma_f32_32x32x16_f16(kf1, qf[s], st1, 0, 0, 0);
        }
        __builtin_amdgcn_s_setprio(0);

        // ---- online softmax max + defer-rescale (THR=8 log2) ----
        float tm = st0[0];
#pragma unroll
        for (int i = 1; i < 16; ++i) tm = fmaxf(tm, st0[i]);
#pragma unroll
        for (int i = 0; i < 16; ++i) tm = fmaxf(tm, st1[i]);
        tm = fmaxf(tm, __shfl_xor(tm, 32));
        if (!__all(tm <= m_s + 8.f)) {
            float mn = fmaxf(m_s, tm);
            float fs = exp2f(m_s - mn);
            m_s = mn;
            if (hi == 0) Fs[w][ql] = fs;
#pragma unroll
            for (int r = 0; r < 16; ++r) {
                float f = Fs[w][(r & 3) + 8 * (r >> 2) + 4 * hi];
                o0[r]   *= f;
                o1[r]   *= f;
                lacc[r] *= f;
            }
        }
        // ---- exps only (sum rides the MFMA below) ----
#pragma unroll
        for (int i = 0; i < 16; ++i) st0[i] = exp2f(st0[i] - m_s);
#pragma unroll
        for (int i = 0; i < 16; ++i) st1[i] = exp2f(st1[i] - m_s);

        // ---- P -> A-frags in-register (cvt_pk + lane^32 exchange) + PV + l ----
        __builtin_amdgcn_s_setprio(1);
#pragma unroll
        for (int tt = 0; tt < 4; ++tt) {
            const int rb = (tt & 1) * 8;
            float v0, v1, v2, v3, v4, v5, v6, v7;
            if (tt < 2) {
                v0 = st0[rb + 0]; v1 = st0[rb + 1]; v2 = st0[rb + 2]; v3 = st0[rb + 3];
                v4 = st0[rb + 4]; v5 = st0[rb + 5]; v6 = st0[rb + 6]; v7 = st0[rb + 7];
            } else {
                v0 = st1[rb + 0]; v1 = st1[rb + 1]; v2 = st1[rb + 2]; v3 = st1[rb + 3];
                v4 = st1[rb + 4]; v5 = st1[rb + 5]; v6 = st1[rb + 6]; v7 = st1[rb + 7];
            }
            union U { fp16x2 h; unsigned u; };
            U ua0; ua0.h = __builtin_amdgcn_cvt_pkrtz(v0, v1);
            U ua1; ua1.h = __builtin_amdgcn_cvt_pkrtz(v2, v3);
            U ub0; ub0.h = __builtin_amdgcn_cvt_pkrtz(v4, v5);
            U ub1; ub1.h = __builtin_amdgcn_cvt_pkrtz(v6, v7);
            const unsigned pa0 = __shfl_xor(ua0.u, 32);
            const unsigned pa1 = __shfl_xor(ua1.u, 32);
            const unsigned pb0 = __shfl_xor(ub0.u, 32);
            const unsigned pb1 = __shfl_xor(ub1.u, 32);
            union A { unsigned u[4]; half8 h8; } pA;
            pA.u[0] = hi ? pb0 : ua0.u;
            pA.u[1] = hi ? pb1 : ua1.u;
            pA.u[2] = hi ? ub0.u : pa0;
            pA.u[3] = hi ? ub1.u : pa1;
            const int cv = 2 * tt + hi;
            {
                const int c0 = ((cv ^ (ql & 7))) * 8;
                half8 vb0 = *reinterpret_cast<const half8*>(&Vs[p][ql][c0]);
                half8 vb1 = *reinterpret_cast<const half8*>(&Vs[p][32 + ql][c0]);
                o0   = __builtin_amdgcn_mfma_f32_32x32x16_f16(pA.h8, vb0, o0, 0, 0, 0);
                o1   = __builtin_amdgcn_mfma_f32_32x32x16_f16(pA.h8, vb1, o1, 0, 0, 0);
                lacc = __builtin_amdgcn_mfma_f32_32x32x16_f16(pA.h8, onesf, lacc, 0, 0, 0);
            }
        }
        __builtin_amdgcn_s_setprio(0);

        p ^= 1;
    }

    // ---- finalize: l is lane-local in PV layout; no barrier needed ----
#pragma unroll
    for (int r = 0; r < 16; ++r) {
        const int qp = (r & 3) + 8 * (r >> 2) + 4 * hi;
        const float inv = 1.0f / lacc[r];
        const int qrow = q0 + w * 32 + qp;
        Op[(poff + qrow) * HDIM + ql]      = (_Float16)(o0[r] * inv);
        Op[(poff + qrow) * HDIM + 32 + ql] = (_Float16)(o1[r] * inv);
    }
    // m per q=ql (QKT layout, hi==0 lanes); l per q=qp (PV layout, ql==0 lanes)
    if (hi == 0) {
        const int qrow = q0 + w * 32 + ql;
        ml[2 * (poff + qrow) + 0] = m_s;
    }
    if (ql == 0) {
#pragma unroll
        for (int r = 0; r < 16; ++r) {
            const int qp = (r & 3) + 8 * (r >> 2) + 4 * hi;
            const int qrow = q0 + w * 32 + qp;
            ml[2 * (poff + qrow) + 1] = lacc[r];
        }
    }
}

// ---------------------------------------------------------------------------
// Merge the KVSPLIT normalized partials -> hd (f16, heads layout).
// ---------------------------------------------------------------------------
__global__ __launch_bounds__(256) void attn_merge(const _Float16* __restrict__ Op,
                                                  const float* __restrict__ ml,
                                                  _Float16* __restrict__ hd) {
    const int t  = threadIdx.x;
    const int q  = blockIdx.x * 64 + (t >> 2);
    const int d0 = (t & 3) * 16;
    const int h  = blockIdx.y;
    const int b  = blockIdx.z;

    size_t offs[KVSPLIT];
    float2 mls[KVSPLIT];
#pragma unroll
    for (int s = 0; s < KVSPLIT; ++s) {
        offs[s] = (((size_t)s * BATCH + b) * NHEADS + h) * SEQ + q;
        mls[s] = reinterpret_cast<const float2*>(ml)[offs[s]];
    }
    float m = mls[0].x;
#pragma unroll
    for (int s = 1; s < KVSPLIT; ++s) m = fmaxf(m, mls[s].x);
    float wgt[KVSPLIT];
    float wsum = 0.f;
#pragma unroll
    for (int s = 0; s < KVSPLIT; ++s) {
        wgt[s] = mls[s].y * exp2f(mls[s].x - m);
        wsum += wgt[s];
    }
    float inv = 1.0f / wsum;

    float o[16] = {};
#pragma unroll
    for (int s = 0; s < KVSPLIT; ++s) {
        const _Float16* pp = Op + offs[s] * HDIM + d0;
        half8 a = *reinterpret_cast<const half8*>(pp);
        half8 c = *reinterpret_cast<const half8*>(pp + 8);
        float wv = wgt[s] * inv;
#pragma unroll
        for (int i = 0; i < 8; ++i) {
            o[i]     += wv * (float)a[i];
            o[8 + i] += wv * (float)c[i];
        }
    }
    half8 o0, o1;
#pragma unroll
    for (int i = 0; i < 8; ++i) { o0[i] = (_Float16)o[i]; o1[i] = (_Float16)o[8 + i]; }
    _Float16* dst = hd + (size_t)(b * SEQ + q) * PROJ + h * HDIM + d0;
    *reinterpret_cast<half8*>(dst)     = o0;
    *reinterpret_cast<half8*>(dst + 8) = o1;
}

// ---------------------------------------------------------------------------
extern "C" void kernel_launch(void* const* d_in, const int* in_sizes, int n_in,
                              void* d_out, int out_size, void* d_ws, size_t ws_size,
                              hipStream_t stream) {
    const float* x  = (const float*)d_in[0];   // (BL, EMBED)
    const float* pW = (const float*)d_in[1];   // (EMBED, PROJ)
    const float* pb = (const float*)d_in[2];   // (PROJ)
    const float* Wq = (const float*)d_in[3];   // (PROJ, PROJ)
    const float* Wk = (const float*)d_in[4];
    const float* Wv = (const float*)d_in[5];
    const float* oW = (const float*)d_in[6];   // (PROJ, EMBED)
    float* out = (float*)d_out;                // (BL, EMBED) fp32

    _Float16* ws    = (_Float16*)d_ws;
    _Float16* p_h   = ws;                                  // BL x PROJ
    _Float16* qkv   = p_h + (size_t)BL * PROJ;             // BL x 1536
    _Float16* hd    = qkv + (size_t)BL * QKVN;             // BL x PROJ
    _Float16* pWt   = hd + (size_t)BL * PROJ;              // PROJ x EMBED
    _Float16* qkvWt = pWt + (size_t)PROJ * EMBED;          // 1536 x PROJ
    _Float16* oWt   = qkvWt + (size_t)QKVN * PROJ;         // EMBED x PROJ
    _Float16* vtb   = oWt + (size_t)EMBED * PROJ;          // B*H*HDIM x SEQ
    _Float16* Oph   = vtb + (size_t)BATCH * NHEADS * HDIM * SEQ;  // KVSPLIT*B*H*SEQ*HDIM f16
    float*    mlb   = (float*)(Oph + (size_t)KVSPLIT * BATCH * NHEADS * SEQ * HDIM);

    dim3 blk(256);

    // ---- fused weight prep (attn scale * log2e folded into Wq) ----
    trconv_all<<<dim3(448), blk, 0, stream>>>(pW, Wq, Wk, Wv, oW, pWt, qkvWt, oWt);

    // ---- p = relu(x @ pW + b), f16 out ----
    gemm_mfma<64, 64, 1, 1, 0><<<dim3(PROJ / 64, BL / 64), blk, 0, stream>>>(
        (const void*)x, pWt, pb, (void*)p_h, BL, PROJ, EMBED);

    // ---- fused q|k|v = p @ [Wq|Wk|Wv], f16 out : 128x128 tile ----
    gemm_mfma<128, 128, 0, 0, 0><<<dim3(QKVN / 128, BL / 128), blk, 0, stream>>>(
        (const void*)p_h, qkvWt, nullptr, (void*)qkv, BL, QKVN, PROJ);

    // ---- pre-transpose V per head ----
    trans_v<<<dim3(SEQ / 64, NHEADS, BATCH), blk, 0, stream>>>(qkv + 2 * PROJ, vtb);

    // ---- attention: split-KV partials (1-D grid, XCD-swizzled) + merge ----
    attn_part<<<dim3((SEQ / 128) * KVSPLIT * NHEADS * BATCH), blk, 0, stream>>>(
        qkv, qkv + PROJ, vtb, Oph, mlb);
    attn_merge<<<dim3(SEQ / 64, NHEADS, BATCH), blk, 0, stream>>>(Oph, mlb, hd);

    // ---- out = heads @ oW, fp32 out ----
    gemm_mfma<128, 64, 0, 0, 1><<<dim3(EMBED / 64, BL / 128), blk, 0, stream>>>(
        (const void*)hd, oWt, nullptr, (void*)out, BL, EMBED, PROJ);
}

// Round 20
// 104.093 us; speedup vs baseline: 1.1214x; 1.1214x over previous
//
#include <hip/hip_runtime.h>
#include <math.h>

#define BATCH 2
#define SEQ 2048
#define BL (BATCH * SEQ)      // 4096
#define EMBED 1024
#define PROJ 512
#define NHEADS 8
#define HDIM 64
#define QKVN (3 * PROJ)       // 1536 fused q|k|v columns
#define KVSPLIT 4
#define KVQ (SEQ / KVSPLIT)   // 512

typedef _Float16 half8 __attribute__((ext_vector_type(8)));
typedef __fp16 fp16x2 __attribute__((ext_vector_type(2)));
typedef float floatx4 __attribute__((ext_vector_type(4)));
typedef float floatx16 __attribute__((ext_vector_type(16)));

// ---------------------------------------------------------------------------
// Fused weight prep: all 5 transposes+converts in one launch.
// ---------------------------------------------------------------------------
__global__ __launch_bounds__(256) void trconv_all(const float* __restrict__ pW,
                                                  const float* __restrict__ Wq,
                                                  const float* __restrict__ Wk,
                                                  const float* __restrict__ Wv,
                                                  const float* __restrict__ oW,
                                                  _Float16* __restrict__ pWt,
                                                  _Float16* __restrict__ qkvWt,
                                                  _Float16* __restrict__ oWt) {
    __shared__ float tile[64][65];
    int id = blockIdx.x;
    const float* src;
    _Float16* dst;
    int K, N;
    float scale = 1.0f;
    if (id < 128)      { src = pW; dst = pWt; K = EMBED; N = PROJ; }
    else if (id < 192) { src = Wq; dst = qkvWt; K = PROJ; N = PROJ;
                         scale = 0.125f * 1.44269504f; id -= 128; }
    else if (id < 256) { src = Wk; dst = qkvWt + (size_t)PROJ * PROJ; K = PROJ; N = PROJ; id -= 192; }
    else if (id < 320) { src = Wv; dst = qkvWt + (size_t)2 * PROJ * PROJ; K = PROJ; N = PROJ; id -= 256; }
    else               { src = oW; dst = oWt; K = PROJ; N = EMBED; id -= 320; }

    const int tn = N / 64;
    const int n0 = (id % tn) * 64;
    const int k0 = (id / tn) * 64;

    const int t  = threadIdx.x;
    const int tx = t & 63;
    const int ty = t >> 6;
#pragma unroll
    for (int i = 0; i < 16; ++i) {
        int k = ty * 16 + i;
        tile[k][tx] = src[(size_t)(k0 + k) * N + n0 + tx];
    }
    __syncthreads();
#pragma unroll
    for (int i = 0; i < 16; ++i) {
        int n = ty * 16 + i;
        dst[(size_t)(n0 + n) * K + k0 + tx] = (_Float16)(tile[tx][n] * scale);
    }
}

// ---------------------------------------------------------------------------
// V pre-transpose: v (f16, rows stride QKVN, head h cols 64) -> vt[b][h][d][SEQ]
// ---------------------------------------------------------------------------
__global__ __launch_bounds__(256) void trans_v(const _Float16* __restrict__ v,
                                               _Float16* __restrict__ vt) {
    __shared__ _Float16 tile[64][72];
    const int t  = threadIdx.x;
    const int t0 = blockIdx.x * 64;
    const int h  = blockIdx.y;
    const int b  = blockIdx.z;
    {
        const int r = t >> 2, c0 = (t & 3) * 16;
        const _Float16* src = v + (size_t)(b * SEQ + t0 + r) * QKVN + h * HDIM + c0;
        *reinterpret_cast<half8*>(&tile[r][c0])     = *reinterpret_cast<const half8*>(src);
        *reinterpret_cast<half8*>(&tile[r][c0 + 8]) = *reinterpret_cast<const half8*>(src + 8);
    }
    __syncthreads();
    {
        const int c = t >> 2, k0 = (t & 3) * 16;
        half8 o1, o2;
#pragma unroll
        for (int i = 0; i < 8; ++i) { o1[i] = tile[k0 + i][c]; o2[i] = tile[k0 + 8 + i][c]; }
        _Float16* dst = vt + ((size_t)(b * NHEADS + h) * HDIM + c) * SEQ + t0 + k0;
        *reinterpret_cast<half8*>(dst)     = o1;
        *reinterpret_cast<half8*>(dst + 8) = o2;
    }
}

// ---------------------------------------------------------------------------
// f16 MFMA GEMM: C[M][N] = A[M][K] @ Bt[N][K]^T (+bias, relu), fp32 accum.
// DOUBLE-BUFFERED LDS, one barrier per K-step.
// ---------------------------------------------------------------------------
template <int BM, int BN, int A_F32, int BIASRELU, int C_F32>
__global__ __launch_bounds__(256) void gemm_mfma(const void* __restrict__ Ap,
                                                 const _Float16* __restrict__ Bt,
                                                 const float* __restrict__ bias,
                                                 void* __restrict__ Cp,
                                                 int M, int N, int K) {
    __shared__ _Float16 Ah[2][BM][40];
    __shared__ _Float16 Bh[2][BN][40];

    constexpr int MF = BM / 32;
    constexpr int NF = BN / 32;
    constexpr int EPA = BM / 8;
    constexpr int TPA = 32 / EPA;
    constexpr int EPB = BN / 8;
    constexpr int TPB = 32 / EPB;

    const int t  = threadIdx.x;
    const int w  = t >> 6;
    const int l  = t & 63;
    const int lr = l & 15;
    const int lg = l >> 4;
    const int bm = blockIdx.y * BM;
    const int bn = blockIdx.x * BN;
    const int wr = w >> 1;
    const int wc = w & 1;

    const int ar = t / TPA, ac = (t % TPA) * EPA;
    const int br = t / TPB, bc = (t % TPB) * EPB;

    floatx4 acc[MF][NF];
#pragma unroll
    for (int i = 0; i < MF; ++i)
#pragma unroll
        for (int j = 0; j < NF; ++j) acc[i][j] = (floatx4){0.f, 0.f, 0.f, 0.f};

    float4 af[EPA / 4];
    half8  ah[EPA / 8];
    half8  bh[EPB / 8];

    const float* Af = (const float*)Ap;
    const _Float16* Ah16 = (const _Float16*)Ap;

    if (A_F32) {
#pragma unroll
        for (int i = 0; i < EPA / 4; ++i)
            af[i] = *reinterpret_cast<const float4*>(&Af[(size_t)(bm + ar) * K + ac + i * 4]);
    } else {
#pragma unroll
        for (int i = 0; i < EPA / 8; ++i)
            ah[i] = *reinterpret_cast<const half8*>(&Ah16[(size_t)(bm + ar) * K + ac + i * 8]);
    }
#pragma unroll
    for (int i = 0; i < EPB / 8; ++i)
        bh[i] = *reinterpret_cast<const half8*>(&Bt[(size_t)(bn + br) * K + bc + i * 8]);

    int pb_ = 0;
    for (int kt = 0; kt < K; kt += 32) {
        if (A_F32) {
#pragma unroll
            for (int i = 0; i < EPA / 8; ++i) {
                half8 hcv;
                float4 a0 = af[2 * i], a1 = af[2 * i + 1];
                hcv[0] = (_Float16)a0.x; hcv[1] = (_Float16)a0.y;
                hcv[2] = (_Float16)a0.z; hcv[3] = (_Float16)a0.w;
                hcv[4] = (_Float16)a1.x; hcv[5] = (_Float16)a1.y;
                hcv[6] = (_Float16)a1.z; hcv[7] = (_Float16)a1.w;
                *reinterpret_cast<half8*>(&Ah[pb_][ar][ac + i * 8]) = hcv;
            }
        } else {
#pragma unroll
            for (int i = 0; i < EPA / 8; ++i)
                *reinterpret_cast<half8*>(&Ah[pb_][ar][ac + i * 8]) = ah[i];
        }
#pragma unroll
        for (int i = 0; i < EPB / 8; ++i)
            *reinterpret_cast<half8*>(&Bh[pb_][br][bc + i * 8]) = bh[i];
        __syncthreads();   // ONE barrier per K-step

        if (kt + 32 < K) {
            if (A_F32) {
#pragma unroll
                for (int i = 0; i < EPA / 4; ++i)
                    af[i] = *reinterpret_cast<const float4*>(&Af[(size_t)(bm + ar) * K + kt + 32 + ac + i * 4]);
            } else {
#pragma unroll
                for (int i = 0; i < EPA / 8; ++i)
                    ah[i] = *reinterpret_cast<const half8*>(&Ah16[(size_t)(bm + ar) * K + kt + 32 + ac + i * 8]);
            }
#pragma unroll
            for (int i = 0; i < EPB / 8; ++i)
                bh[i] = *reinterpret_cast<const half8*>(&Bt[(size_t)(bn + br) * K + kt + 32 + bc + i * 8]);
        }

        half8 afr[MF], bfr[NF];
#pragma unroll
        for (int mf = 0; mf < MF; ++mf)
            afr[mf] = *reinterpret_cast<const half8*>(&Ah[pb_][wr * (BM / 2) + mf * 16 + lr][lg * 8]);
#pragma unroll
        for (int nf = 0; nf < NF; ++nf)
            bfr[nf] = *reinterpret_cast<const half8*>(&Bh[pb_][wc * (BN / 2) + nf * 16 + lr][lg * 8]);
        __builtin_amdgcn_s_setprio(1);
#pragma unroll
        for (int mf = 0; mf < MF; ++mf)
#pragma unroll
            for (int nf = 0; nf < NF; ++nf)
                acc[mf][nf] = __builtin_amdgcn_mfma_f32_16x16x32_f16(afr[mf], bfr[nf], acc[mf][nf], 0, 0, 0);
        __builtin_amdgcn_s_setprio(0);

        pb_ ^= 1;
    }

#pragma unroll
    for (int mf = 0; mf < MF; ++mf)
#pragma unroll
        for (int nf = 0; nf < NF; ++nf) {
            const int n = bn + wc * (BN / 2) + nf * 16 + lr;
            float bs = 0.f;
            if (BIASRELU) bs = bias[n];
#pragma unroll
            for (int r = 0; r < 4; ++r) {
                const int m = bm + wr * (BM / 2) + mf * 16 + lg * 4 + r;
                float v = acc[mf][nf][r];
                if (BIASRELU) v = fmaxf(v + bs, 0.f);
                if (C_F32)
                    ((float*)Cp)[(size_t)m * N + n] = v;
                else
                    ((_Float16*)Cp)[(size_t)m * N + n] = (_Float16)v;
            }
        }
}

// ---------------------------------------------------------------------------
// f16-MFMA flash attention v3.4 (R18 known-good): R12 structure + T1 XCD
// swizzle. 1-D grid of 1024 blocks; chunked remap so each XCD owns 8
// complete KV-groups -> K/V fetched once per L2.
// ---------------------------------------------------------------------------
__global__ __launch_bounds__(256, 4) void attn_part(const _Float16* __restrict__ Q,
                                                    const _Float16* __restrict__ K,
                                                    const _Float16* __restrict__ Vt,
                                                    _Float16* __restrict__ Op,
                                                    float* __restrict__ ml) {
    __shared__ _Float16 Ks[2][64][64];
    __shared__ _Float16 Vs[2][64][64];
    __shared__ float Fs[4][32];

    const int t  = threadIdx.x;
    const int w  = t >> 6;
    const int l  = t & 63;
    const int ql = l & 31;
    const int hi = l >> 5;

    // ---- T1 chunked XCD swizzle (bijective: 1024 = 8 XCDs x 128) ----
    const int lin     = blockIdx.x;
    const int logical = (lin & 7) * 128 + (lin >> 3);
    const int qt  = logical & 15;          // 0..15
    const int g   = logical >> 4;          // 0..63 : (kvs,h,b) group
    const int kvs = g & 3;
    const int h   = (g >> 2) & 7;
    const int b   = g >> 5;                // 0..1

    const int q0  = qt * 128;
    const size_t base  = (size_t)b * SEQ * QKVN + (size_t)h * HDIM;
    const size_t vbase = (size_t)(b * NHEADS + h) * HDIM * SEQ;
    const size_t poff  = (((size_t)kvs * BATCH + b) * NHEADS + h) * SEQ;

    const int kt0  = kvs * KVQ;
    const int kend = kt0 + KVQ;

    half8 qf[4];
#pragma unroll
    for (int s = 0; s < 4; ++s)
        qf[s] = *reinterpret_cast<const half8*>(
            &Q[base + (size_t)(q0 + w * 32 + ql) * QKVN + s * 16 + hi * 8]);

    floatx16 o0 = (floatx16)0.f, o1 = (floatx16)0.f;
    float m_s = -1e30f, l_s = 0.f;

    const int rkv  = t >> 2;
    const int c8   = (t & 3) * 2;
    const int swz0 = (c8 ^ (rkv & 7)) * 8;
    const int swz1 = ((c8 + 1) ^ (rkv & 7)) * 8;

    half8 ka0, ka1, va0, va1;
    {
        const _Float16* kp = K + base + (size_t)(kt0 + rkv) * QKVN + c8 * 8;
        ka0 = *reinterpret_cast<const half8*>(kp);
        ka1 = *reinterpret_cast<const half8*>(kp + 8);
        const _Float16* vp = Vt + vbase + (size_t)rkv * SEQ + kt0 + c8 * 8;
        va0 = *reinterpret_cast<const half8*>(vp);
        va1 = *reinterpret_cast<const half8*>(vp + 8);
    }

    int p = 0;
    for (int kt = kt0; kt < kend; kt += 64) {
        *reinterpret_cast<half8*>(&Ks[p][rkv][swz0]) = ka0;
        *reinterpret_cast<half8*>(&Ks[p][rkv][swz1]) = ka1;
        *reinterpret_cast<half8*>(&Vs[p][rkv][swz0]) = va0;
        *reinterpret_cast<half8*>(&Vs[p][rkv][swz1]) = va1;
        __syncthreads();

        if (kt + 64 < kend) {
            const _Float16* kp = K + base + (size_t)(kt + 64 + rkv) * QKVN + c8 * 8;
            ka0 = *reinterpret_cast<const half8*>(kp);
            ka1 = *reinterpret_cast<const half8*>(kp + 8);
            const _Float16* vp = Vt + vbase + (size_t)rkv * SEQ + (kt + 64) + c8 * 8;
            va0 = *reinterpret_cast<const half8*>(vp);
            va1 = *reinterpret_cast<const half8*>(vp + 8);
        }

        // ---- S^T = K @ Q^T (log2 domain) ----
        floatx16 st0 = (floatx16)0.f, st1 = (floatx16)0.f;
        __builtin_amdgcn_s_setprio(1);
#pragma unroll
        for (int s = 0; s < 4; ++s) {
            const int c0 = ((2 * s + hi) ^ (ql & 7)) * 8;
            half8 kf0 = *reinterpret_cast<const half8*>(&Ks[p][ql][c0]);
            half8 kf1 = *reinterpret_cast<const half8*>(&Ks[p][32 + ql][c0]);
            st0 = __builtin_amdgcn_mfma_f32_32x32x16_f16(kf0, qf[s], st0, 0, 0, 0);
            st1 = __builtin_amdgcn_mfma_f32_32x32x16_f16(kf1, qf[s], st1, 0, 0, 0);
        }
        __builtin_amdgcn_s_setprio(0);

        // ---- online softmax, defer-rescale (THR=8 log2) ----
        float tm = st0[0];
#pragma unroll
        for (int i = 1; i < 16; ++i) tm = fmaxf(tm, st0[i]);
#pragma unroll
        for (int i = 0; i < 16; ++i) tm = fmaxf(tm, st1[i]);
        tm = fmaxf(tm, __shfl_xor(tm, 32));
        if (!__all(tm <= m_s + 8.f)) {
            float mn = fmaxf(m_s, tm);
            float fs = exp2f(m_s - mn);
            m_s = mn;
            l_s *= fs;
            if (hi == 0) Fs[w][ql] = fs;
#pragma unroll
            for (int r = 0; r < 16; ++r) {
                float f = Fs[w][(r & 3) + 8 * (r >> 2) + 4 * hi];
                o0[r] *= f;
                o1[r] *= f;
            }
        }
        float sum = 0.f;
#pragma unroll
        for (int i = 0; i < 16; ++i) { float pv = exp2f(st0[i] - m_s); st0[i] = pv; sum += pv; }
#pragma unroll
        for (int i = 0; i < 16; ++i) { float pv = exp2f(st1[i] - m_s); st1[i] = pv; sum += pv; }
        sum += __shfl_xor(sum, 32);
        l_s += sum;

        // ---- P -> A-frags in-register (cvt_pk + lane^32 exchange) + PV ----
        __builtin_amdgcn_s_setprio(1);
#pragma unroll
        for (int tt = 0; tt < 4; ++tt) {
            const int rb = (tt & 1) * 8;
            float v0, v1, v2, v3, v4, v5, v6, v7;
            if (tt < 2) {
                v0 = st0[rb + 0]; v1 = st0[rb + 1]; v2 = st0[rb + 2]; v3 = st0[rb + 3];
                v4 = st0[rb + 4]; v5 = st0[rb + 5]; v6 = st0[rb + 6]; v7 = st0[rb + 7];
            } else {
                v0 = st1[rb + 0]; v1 = st1[rb + 1]; v2 = st1[rb + 2]; v3 = st1[rb + 3];
                v4 = st1[rb + 4]; v5 = st1[rb + 5]; v6 = st1[rb + 6]; v7 = st1[rb + 7];
            }
            union U { fp16x2 h; unsigned u; };
            U ua0; ua0.h = __builtin_amdgcn_cvt_pkrtz(v0, v1);
            U ua1; ua1.h = __builtin_amdgcn_cvt_pkrtz(v2, v3);
            U ub0; ub0.h = __builtin_amdgcn_cvt_pkrtz(v4, v5);
            U ub1; ub1.h = __builtin_amdgcn_cvt_pkrtz(v6, v7);
            const unsigned pa0 = __shfl_xor(ua0.u, 32);
            const unsigned pa1 = __shfl_xor(ua1.u, 32);
            const unsigned pb0 = __shfl_xor(ub0.u, 32);
            const unsigned pb1 = __shfl_xor(ub1.u, 32);
            union A { unsigned u[4]; half8 h8; } pA;
            pA.u[0] = hi ? pb0 : ua0.u;
            pA.u[1] = hi ? pb1 : ua1.u;
            pA.u[2] = hi ? ub0.u : pa0;
            pA.u[3] = hi ? ub1.u : pa1;
            const int cv = 2 * tt + hi;
            {
                const int c0 = ((cv ^ (ql & 7))) * 8;
                half8 vb0 = *reinterpret_cast<const half8*>(&Vs[p][ql][c0]);
                half8 vb1 = *reinterpret_cast<const half8*>(&Vs[p][32 + ql][c0]);
                o0 = __builtin_amdgcn_mfma_f32_32x32x16_f16(pA.h8, vb0, o0, 0, 0, 0);
                o1 = __builtin_amdgcn_mfma_f32_32x32x16_f16(pA.h8, vb1, o1, 0, 0, 0);
            }
        }
        __builtin_amdgcn_s_setprio(0);

        p ^= 1;
    }

    // ---- finalize ----
    __syncthreads();
    if (hi == 0) Fs[w][ql] = l_s;
#pragma unroll
    for (int r = 0; r < 16; ++r) {
        const int qp = (r & 3) + 8 * (r >> 2) + 4 * hi;
        const float inv = 1.0f / Fs[w][qp];
        const int qrow = q0 + w * 32 + qp;
        Op[(poff + qrow) * HDIM + ql]      = (_Float16)(o0[r] * inv);
        Op[(poff + qrow) * HDIM + 32 + ql] = (_Float16)(o1[r] * inv);
    }
    if (hi == 0) {
        const int qrow = q0 + w * 32 + ql;
        reinterpret_cast<float2*>(ml)[poff + qrow] = make_float2(m_s, l_s);
    }
}

// ---------------------------------------------------------------------------
// Merge the KVSPLIT normalized partials -> hd (f16, heads layout).
// ---------------------------------------------------------------------------
__global__ __launch_bounds__(256) void attn_merge(const _Float16* __restrict__ Op,
                                                  const float* __restrict__ ml,
                                                  _Float16* __restrict__ hd) {
    const int t  = threadIdx.x;
    const int q  = blockIdx.x * 64 + (t >> 2);
    const int d0 = (t & 3) * 16;
    const int h  = blockIdx.y;
    const int b  = blockIdx.z;

    size_t offs[KVSPLIT];
    float2 mls[KVSPLIT];
#pragma unroll
    for (int s = 0; s < KVSPLIT; ++s) {
        offs[s] = (((size_t)s * BATCH + b) * NHEADS + h) * SEQ + q;
        mls[s] = reinterpret_cast<const float2*>(ml)[offs[s]];
    }
    float m = mls[0].x;
#pragma unroll
    for (int s = 1; s < KVSPLIT; ++s) m = fmaxf(m, mls[s].x);
    float wgt[KVSPLIT];
    float wsum = 0.f;
#pragma unroll
    for (int s = 0; s < KVSPLIT; ++s) {
        wgt[s] = mls[s].y * exp2f(mls[s].x - m);
        wsum += wgt[s];
    }
    float inv = 1.0f / wsum;

    float o[16] = {};
#pragma unroll
    for (int s = 0; s < KVSPLIT; ++s) {
        const _Float16* pp = Op + offs[s] * HDIM + d0;
        half8 a = *reinterpret_cast<const half8*>(pp);
        half8 c = *reinterpret_cast<const half8*>(pp + 8);
        float wv = wgt[s] * inv;
#pragma unroll
        for (int i = 0; i < 8; ++i) {
            o[i]     += wv * (float)a[i];
            o[8 + i] += wv * (float)c[i];
        }
    }
    half8 o0, o1;
#pragma unroll
    for (int i = 0; i < 8; ++i) { o0[i] = (_Float16)o[i]; o1[i] = (_Float16)o[8 + i]; }
    _Float16* dst = hd + (size_t)(b * SEQ + q) * PROJ + h * HDIM + d0;
    *reinterpret_cast<half8*>(dst)     = o0;
    *reinterpret_cast<half8*>(dst + 8) = o1;
}

// ---------------------------------------------------------------------------
extern "C" void kernel_launch(void* const* d_in, const int* in_sizes, int n_in,
                              void* d_out, int out_size, void* d_ws, size_t ws_size,
                              hipStream_t stream) {
    const float* x  = (const float*)d_in[0];   // (BL, EMBED)
    const float* pW = (const float*)d_in[1];   // (EMBED, PROJ)
    const float* pb = (const float*)d_in[2];   // (PROJ)
    const float* Wq = (const float*)d_in[3];   // (PROJ, PROJ)
    const float* Wk = (const float*)d_in[4];
    const float* Wv = (const float*)d_in[5];
    const float* oW = (const float*)d_in[6];   // (PROJ, EMBED)
    float* out = (float*)d_out;                // (BL, EMBED) fp32

    _Float16* ws    = (_Float16*)d_ws;
    _Float16* p_h   = ws;                                  // BL x PROJ
    _Float16* qkv   = p_h + (size_t)BL * PROJ;             // BL x 1536
    _Float16* hd    = qkv + (size_t)BL * QKVN;             // BL x PROJ
    _Float16* pWt   = hd + (size_t)BL * PROJ;              // PROJ x EMBED
    _Float16* qkvWt = pWt + (size_t)PROJ * EMBED;          // 1536 x PROJ
    _Float16* oWt   = qkvWt + (size_t)QKVN * PROJ;         // EMBED x PROJ
    _Float16* vtb   = oWt + (size_t)EMBED * PROJ;          // B*H*HDIM x SEQ
    _Float16* Oph   = vtb + (size_t)BATCH * NHEADS * HDIM * SEQ;  // KVSPLIT*B*H*SEQ*HDIM f16
    float*    mlb   = (float*)(Oph + (size_t)KVSPLIT * BATCH * NHEADS * SEQ * HDIM);

    dim3 blk(256);

    // ---- fused weight prep (attn scale * log2e folded into Wq) ----
    trconv_all<<<dim3(448), blk, 0, stream>>>(pW, Wq, Wk, Wv, oW, pWt, qkvWt, oWt);

    // ---- p = relu(x @ pW + b), f16 out ----
    gemm_mfma<64, 64, 1, 1, 0><<<dim3(PROJ / 64, BL / 64), blk, 0, stream>>>(
        (const void*)x, pWt, pb, (void*)p_h, BL, PROJ, EMBED);

    // ---- fused q|k|v = p @ [Wq|Wk|Wv], f16 out : 128x128 tile ----
    gemm_mfma<128, 128, 0, 0, 0><<<dim3(QKVN / 128, BL / 128), blk, 0, stream>>>(
        (const void*)p_h, qkvWt, nullptr, (void*)qkv, BL, QKVN, PROJ);

    // ---- pre-transpose V per head ----
    trans_v<<<dim3(SEQ / 64, NHEADS, BATCH), blk, 0, stream>>>(qkv + 2 * PROJ, vtb);

    // ---- attention: split-KV partials (1-D grid, XCD-swizzled) + merge ----
    attn_part<<<dim3((SEQ / 128) * KVSPLIT * NHEADS * BATCH), blk, 0, stream>>>(
        qkv, qkv + PROJ, vtb, Oph, mlb);
    attn_merge<<<dim3(SEQ / 64, NHEADS, BATCH), blk, 0, stream>>>(Oph, mlb, hd);

    // ---- out = heads @ oW, fp32 out ----
    gemm_mfma<128, 64, 0, 0, 1><<<dim3(EMBED / 64, BL / 128), blk, 0, stream>>>(
        (const void*)hd, oWt, nullptr, (void*)out, BL, EMBED, PROJ);
}

// Round 21
// 99.957 us; speedup vs baseline: 1.1678x; 1.0414x over previous
//
#include <hip/hip_runtime.h>
#include <math.h>

#define BATCH 2
#define SEQ 2048
#define BL (BATCH * SEQ)      // 4096
#define EMBED 1024
#define PROJ 512
#define NHEADS 8
#define HDIM 64
#define QKVN (3 * PROJ)       // 1536 fused q|k|v columns
#define KVSPLIT 4
#define KVQ (SEQ / KVSPLIT)   // 512

typedef _Float16 half8 __attribute__((ext_vector_type(8)));
typedef __fp16 fp16x2 __attribute__((ext_vector_type(2)));
typedef float floatx4 __attribute__((ext_vector_type(4)));
typedef float floatx16 __attribute__((ext_vector_type(16)));

// ---------------------------------------------------------------------------
// Fused weight prep: all 5 transposes+converts in one launch.
// ---------------------------------------------------------------------------
__global__ __launch_bounds__(256) void trconv_all(const float* __restrict__ pW,
                                                  const float* __restrict__ Wq,
                                                  const float* __restrict__ Wk,
                                                  const float* __restrict__ Wv,
                                                  const float* __restrict__ oW,
                                                  _Float16* __restrict__ pWt,
                                                  _Float16* __restrict__ qkvWt,
                                                  _Float16* __restrict__ oWt) {
    __shared__ float tile[64][65];
    int id = blockIdx.x;
    const float* src;
    _Float16* dst;
    int K, N;
    float scale = 1.0f;
    if (id < 128)      { src = pW; dst = pWt; K = EMBED; N = PROJ; }
    else if (id < 192) { src = Wq; dst = qkvWt; K = PROJ; N = PROJ;
                         scale = 0.125f * 1.44269504f; id -= 128; }
    else if (id < 256) { src = Wk; dst = qkvWt + (size_t)PROJ * PROJ; K = PROJ; N = PROJ; id -= 192; }
    else if (id < 320) { src = Wv; dst = qkvWt + (size_t)2 * PROJ * PROJ; K = PROJ; N = PROJ; id -= 256; }
    else               { src = oW; dst = oWt; K = PROJ; N = EMBED; id -= 320; }

    const int tn = N / 64;
    const int n0 = (id % tn) * 64;
    const int k0 = (id / tn) * 64;

    const int t  = threadIdx.x;
    const int tx = t & 63;
    const int ty = t >> 6;
#pragma unroll
    for (int i = 0; i < 16; ++i) {
        int k = ty * 16 + i;
        tile[k][tx] = src[(size_t)(k0 + k) * N + n0 + tx];
    }
    __syncthreads();
#pragma unroll
    for (int i = 0; i < 16; ++i) {
        int n = ty * 16 + i;
        dst[(size_t)(n0 + n) * K + k0 + tx] = (_Float16)(tile[tx][n] * scale);
    }
}

// ---------------------------------------------------------------------------
// V pre-transpose: v (f16, rows stride QKVN, head h cols 64) -> vt[b][h][d][SEQ]
// ---------------------------------------------------------------------------
__global__ __launch_bounds__(256) void trans_v(const _Float16* __restrict__ v,
                                               _Float16* __restrict__ vt) {
    __shared__ _Float16 tile[64][72];
    const int t  = threadIdx.x;
    const int t0 = blockIdx.x * 64;
    const int h  = blockIdx.y;
    const int b  = blockIdx.z;
    {
        const int r = t >> 2, c0 = (t & 3) * 16;
        const _Float16* src = v + (size_t)(b * SEQ + t0 + r) * QKVN + h * HDIM + c0;
        *reinterpret_cast<half8*>(&tile[r][c0])     = *reinterpret_cast<const half8*>(src);
        *reinterpret_cast<half8*>(&tile[r][c0 + 8]) = *reinterpret_cast<const half8*>(src + 8);
    }
    __syncthreads();
    {
        const int c = t >> 2, k0 = (t & 3) * 16;
        half8 o1, o2;
#pragma unroll
        for (int i = 0; i < 8; ++i) { o1[i] = tile[k0 + i][c]; o2[i] = tile[k0 + 8 + i][c]; }
        _Float16* dst = vt + ((size_t)(b * NHEADS + h) * HDIM + c) * SEQ + t0 + k0;
        *reinterpret_cast<half8*>(dst)     = o1;
        *reinterpret_cast<half8*>(dst + 8) = o2;
    }
}

// ---------------------------------------------------------------------------
// f16 MFMA GEMM: C[M][N] = A[M][K] @ Bt[N][K]^T (+bias, relu), fp32 accum.
// DOUBLE-BUFFERED LDS, one barrier per K-step.
// 1-D grid + T1 chunked XCD swizzle (grid must be divisible by 8): each XCD
// gets a contiguous run of logical tiles -> A-panels fetched once per L2.
// ---------------------------------------------------------------------------
template <int BM, int BN, int A_F32, int BIASRELU, int C_F32>
__global__ __launch_bounds__(256) void gemm_mfma(const void* __restrict__ Ap,
                                                 const _Float16* __restrict__ Bt,
                                                 const float* __restrict__ bias,
                                                 void* __restrict__ Cp,
                                                 int M, int N, int K, int GX) {
    __shared__ _Float16 Ah[2][BM][40];
    __shared__ _Float16 Bh[2][BN][40];

    constexpr int MF = BM / 32;
    constexpr int NF = BN / 32;
    constexpr int EPA = BM / 8;
    constexpr int TPA = 32 / EPA;
    constexpr int EPB = BN / 8;
    constexpr int TPB = 32 / EPB;

    const int t  = threadIdx.x;
    const int w  = t >> 6;
    const int l  = t & 63;
    const int lr = l & 15;
    const int lg = l >> 4;

    // ---- T1 chunked XCD swizzle ----
    const int lin     = blockIdx.x;
    const int cpx     = gridDim.x >> 3;          // blocks per XCD chunk
    const int logical = (lin & 7) * cpx + (lin >> 3);
    const int bm = (logical / GX) * BM;
    const int bn = (logical % GX) * BN;

    const int wr = w >> 1;
    const int wc = w & 1;

    const int ar = t / TPA, ac = (t % TPA) * EPA;
    const int br = t / TPB, bc = (t % TPB) * EPB;

    floatx4 acc[MF][NF];
#pragma unroll
    for (int i = 0; i < MF; ++i)
#pragma unroll
        for (int j = 0; j < NF; ++j) acc[i][j] = (floatx4){0.f, 0.f, 0.f, 0.f};

    float4 af[EPA / 4];
    half8  ah[EPA / 8];
    half8  bh[EPB / 8];

    const float* Af = (const float*)Ap;
    const _Float16* Ah16 = (const _Float16*)Ap;

    if (A_F32) {
#pragma unroll
        for (int i = 0; i < EPA / 4; ++i)
            af[i] = *reinterpret_cast<const float4*>(&Af[(size_t)(bm + ar) * K + ac + i * 4]);
    } else {
#pragma unroll
        for (int i = 0; i < EPA / 8; ++i)
            ah[i] = *reinterpret_cast<const half8*>(&Ah16[(size_t)(bm + ar) * K + ac + i * 8]);
    }
#pragma unroll
    for (int i = 0; i < EPB / 8; ++i)
        bh[i] = *reinterpret_cast<const half8*>(&Bt[(size_t)(bn + br) * K + bc + i * 8]);

    int pb_ = 0;
    for (int kt = 0; kt < K; kt += 32) {
        if (A_F32) {
#pragma unroll
            for (int i = 0; i < EPA / 8; ++i) {
                half8 hcv;
                float4 a0 = af[2 * i], a1 = af[2 * i + 1];
                hcv[0] = (_Float16)a0.x; hcv[1] = (_Float16)a0.y;
                hcv[2] = (_Float16)a0.z; hcv[3] = (_Float16)a0.w;
                hcv[4] = (_Float16)a1.x; hcv[5] = (_Float16)a1.y;
                hcv[6] = (_Float16)a1.z; hcv[7] = (_Float16)a1.w;
                *reinterpret_cast<half8*>(&Ah[pb_][ar][ac + i * 8]) = hcv;
            }
        } else {
#pragma unroll
            for (int i = 0; i < EPA / 8; ++i)
                *reinterpret_cast<half8*>(&Ah[pb_][ar][ac + i * 8]) = ah[i];
        }
#pragma unroll
        for (int i = 0; i < EPB / 8; ++i)
            *reinterpret_cast<half8*>(&Bh[pb_][br][bc + i * 8]) = bh[i];
        __syncthreads();   // ONE barrier per K-step

        if (kt + 32 < K) {
            if (A_F32) {
#pragma unroll
                for (int i = 0; i < EPA / 4; ++i)
                    af[i] = *reinterpret_cast<const float4*>(&Af[(size_t)(bm + ar) * K + kt + 32 + ac + i * 4]);
            } else {
#pragma unroll
                for (int i = 0; i < EPA / 8; ++i)
                    ah[i] = *reinterpret_cast<const half8*>(&Ah16[(size_t)(bm + ar) * K + kt + 32 + ac + i * 8]);
            }
#pragma unroll
            for (int i = 0; i < EPB / 8; ++i)
                bh[i] = *reinterpret_cast<const half8*>(&Bt[(size_t)(bn + br) * K + kt + 32 + bc + i * 8]);
        }

        half8 afr[MF], bfr[NF];
#pragma unroll
        for (int mf = 0; mf < MF; ++mf)
            afr[mf] = *reinterpret_cast<const half8*>(&Ah[pb_][wr * (BM / 2) + mf * 16 + lr][lg * 8]);
#pragma unroll
        for (int nf = 0; nf < NF; ++nf)
            bfr[nf] = *reinterpret_cast<const half8*>(&Bh[pb_][wc * (BN / 2) + nf * 16 + lr][lg * 8]);
        __builtin_amdgcn_s_setprio(1);
#pragma unroll
        for (int mf = 0; mf < MF; ++mf)
#pragma unroll
            for (int nf = 0; nf < NF; ++nf)
                acc[mf][nf] = __builtin_amdgcn_mfma_f32_16x16x32_f16(afr[mf], bfr[nf], acc[mf][nf], 0, 0, 0);
        __builtin_amdgcn_s_setprio(0);

        pb_ ^= 1;
    }

#pragma unroll
    for (int mf = 0; mf < MF; ++mf)
#pragma unroll
        for (int nf = 0; nf < NF; ++nf) {
            const int n = bn + wc * (BN / 2) + nf * 16 + lr;
            float bs = 0.f;
            if (BIASRELU) bs = bias[n];
#pragma unroll
            for (int r = 0; r < 4; ++r) {
                const int m = bm + wr * (BM / 2) + mf * 16 + lg * 4 + r;
                float v = acc[mf][nf][r];
                if (BIASRELU) v = fmaxf(v + bs, 0.f);
                if (C_F32)
                    ((float*)Cp)[(size_t)m * N + n] = v;
                else
                    ((_Float16*)Cp)[(size_t)m * N + n] = (_Float16)v;
            }
        }
}

// ---------------------------------------------------------------------------
// f16-MFMA flash attention v3.4 (R18/R20 known-good): R12 structure + T1 XCD
// swizzle. 1-D grid of 1024 blocks; chunked remap so each XCD owns 8
// complete KV-groups -> K/V fetched once per L2.
// ---------------------------------------------------------------------------
__global__ __launch_bounds__(256, 4) void attn_part(const _Float16* __restrict__ Q,
                                                    const _Float16* __restrict__ K,
                                                    const _Float16* __restrict__ Vt,
                                                    _Float16* __restrict__ Op,
                                                    float* __restrict__ ml) {
    __shared__ _Float16 Ks[2][64][64];
    __shared__ _Float16 Vs[2][64][64];
    __shared__ float Fs[4][32];

    const int t  = threadIdx.x;
    const int w  = t >> 6;
    const int l  = t & 63;
    const int ql = l & 31;
    const int hi = l >> 5;

    // ---- T1 chunked XCD swizzle (bijective: 1024 = 8 XCDs x 128) ----
    const int lin     = blockIdx.x;
    const int logical = (lin & 7) * 128 + (lin >> 3);
    const int qt  = logical & 15;          // 0..15
    const int g   = logical >> 4;          // 0..63 : (kvs,h,b) group
    const int kvs = g & 3;
    const int h   = (g >> 2) & 7;
    const int b   = g >> 5;                // 0..1

    const int q0  = qt * 128;
    const size_t base  = (size_t)b * SEQ * QKVN + (size_t)h * HDIM;
    const size_t vbase = (size_t)(b * NHEADS + h) * HDIM * SEQ;
    const size_t poff  = (((size_t)kvs * BATCH + b) * NHEADS + h) * SEQ;

    const int kt0  = kvs * KVQ;
    const int kend = kt0 + KVQ;

    half8 qf[4];
#pragma unroll
    for (int s = 0; s < 4; ++s)
        qf[s] = *reinterpret_cast<const half8*>(
            &Q[base + (size_t)(q0 + w * 32 + ql) * QKVN + s * 16 + hi * 8]);

    floatx16 o0 = (floatx16)0.f, o1 = (floatx16)0.f;
    float m_s = -1e30f, l_s = 0.f;

    const int rkv  = t >> 2;
    const int c8   = (t & 3) * 2;
    const int swz0 = (c8 ^ (rkv & 7)) * 8;
    const int swz1 = ((c8 + 1) ^ (rkv & 7)) * 8;

    half8 ka0, ka1, va0, va1;
    {
        const _Float16* kp = K + base + (size_t)(kt0 + rkv) * QKVN + c8 * 8;
        ka0 = *reinterpret_cast<const half8*>(kp);
        ka1 = *reinterpret_cast<const half8*>(kp + 8);
        const _Float16* vp = Vt + vbase + (size_t)rkv * SEQ + kt0 + c8 * 8;
        va0 = *reinterpret_cast<const half8*>(vp);
        va1 = *reinterpret_cast<const half8*>(vp + 8);
    }

    int p = 0;
    for (int kt = kt0; kt < kend; kt += 64) {
        *reinterpret_cast<half8*>(&Ks[p][rkv][swz0]) = ka0;
        *reinterpret_cast<half8*>(&Ks[p][rkv][swz1]) = ka1;
        *reinterpret_cast<half8*>(&Vs[p][rkv][swz0]) = va0;
        *reinterpret_cast<half8*>(&Vs[p][rkv][swz1]) = va1;
        __syncthreads();

        if (kt + 64 < kend) {
            const _Float16* kp = K + base + (size_t)(kt + 64 + rkv) * QKVN + c8 * 8;
            ka0 = *reinterpret_cast<const half8*>(kp);
            ka1 = *reinterpret_cast<const half8*>(kp + 8);
            const _Float16* vp = Vt + vbase + (size_t)rkv * SEQ + (kt + 64) + c8 * 8;
            va0 = *reinterpret_cast<const half8*>(vp);
            va1 = *reinterpret_cast<const half8*>(vp + 8);
        }

        // ---- S^T = K @ Q^T (log2 domain) ----
        floatx16 st0 = (floatx16)0.f, st1 = (floatx16)0.f;
        __builtin_amdgcn_s_setprio(1);
#pragma unroll
        for (int s = 0; s < 4; ++s) {
            const int c0 = ((2 * s + hi) ^ (ql & 7)) * 8;
            half8 kf0 = *reinterpret_cast<const half8*>(&Ks[p][ql][c0]);
            half8 kf1 = *reinterpret_cast<const half8*>(&Ks[p][32 + ql][c0]);
            st0 = __builtin_amdgcn_mfma_f32_32x32x16_f16(kf0, qf[s], st0, 0, 0, 0);
            st1 = __builtin_amdgcn_mfma_f32_32x32x16_f16(kf1, qf[s], st1, 0, 0, 0);
        }
        __builtin_amdgcn_s_setprio(0);

        // ---- online softmax, defer-rescale (THR=8 log2) ----
        float tm = st0[0];
#pragma unroll
        for (int i = 1; i < 16; ++i) tm = fmaxf(tm, st0[i]);
#pragma unroll
        for (int i = 0; i < 16; ++i) tm = fmaxf(tm, st1[i]);
        tm = fmaxf(tm, __shfl_xor(tm, 32));
        if (!__all(tm <= m_s + 8.f)) {
            float mn = fmaxf(m_s, tm);
            float fs = exp2f(m_s - mn);
            m_s = mn;
            l_s *= fs;
            if (hi == 0) Fs[w][ql] = fs;
#pragma unroll
            for (int r = 0; r < 16; ++r) {
                float f = Fs[w][(r & 3) + 8 * (r >> 2) + 4 * hi];
                o0[r] *= f;
                o1[r] *= f;
            }
        }
        float sum = 0.f;
#pragma unroll
        for (int i = 0; i < 16; ++i) { float pv = exp2f(st0[i] - m_s); st0[i] = pv; sum += pv; }
#pragma unroll
        for (int i = 0; i < 16; ++i) { float pv = exp2f(st1[i] - m_s); st1[i] = pv; sum += pv; }
        sum += __shfl_xor(sum, 32);
        l_s += sum;

        // ---- P -> A-frags in-register (cvt_pk + lane^32 exchange) + PV ----
        __builtin_amdgcn_s_setprio(1);
#pragma unroll
        for (int tt = 0; tt < 4; ++tt) {
            const int rb = (tt & 1) * 8;
            float v0, v1, v2, v3, v4, v5, v6, v7;
            if (tt < 2) {
                v0 = st0[rb + 0]; v1 = st0[rb + 1]; v2 = st0[rb + 2]; v3 = st0[rb + 3];
                v4 = st0[rb + 4]; v5 = st0[rb + 5]; v6 = st0[rb + 6]; v7 = st0[rb + 7];
            } else {
                v0 = st1[rb + 0]; v1 = st1[rb + 1]; v2 = st1[rb + 2]; v3 = st1[rb + 3];
                v4 = st1[rb + 4]; v5 = st1[rb + 5]; v6 = st1[rb + 6]; v7 = st1[rb + 7];
            }
            union U { fp16x2 h; unsigned u; };
            U ua0; ua0.h = __builtin_amdgcn_cvt_pkrtz(v0, v1);
            U ua1; ua1.h = __builtin_amdgcn_cvt_pkrtz(v2, v3);
            U ub0; ub0.h = __builtin_amdgcn_cvt_pkrtz(v4, v5);
            U ub1; ub1.h = __builtin_amdgcn_cvt_pkrtz(v6, v7);
            const unsigned pa0 = __shfl_xor(ua0.u, 32);
            const unsigned pa1 = __shfl_xor(ua1.u, 32);
            const unsigned pb0 = __shfl_xor(ub0.u, 32);
            const unsigned pb1 = __shfl_xor(ub1.u, 32);
            union A { unsigned u[4]; half8 h8; } pA;
            pA.u[0] = hi ? pb0 : ua0.u;
            pA.u[1] = hi ? pb1 : ua1.u;
            pA.u[2] = hi ? ub0.u : pa0;
            pA.u[3] = hi ? ub1.u : pa1;
            const int cv = 2 * tt + hi;
            {
                const int c0 = ((cv ^ (ql & 7))) * 8;
                half8 vb0 = *reinterpret_cast<const half8*>(&Vs[p][ql][c0]);
                half8 vb1 = *reinterpret_cast<const half8*>(&Vs[p][32 + ql][c0]);
                o0 = __builtin_amdgcn_mfma_f32_32x32x16_f16(pA.h8, vb0, o0, 0, 0, 0);
                o1 = __builtin_amdgcn_mfma_f32_32x32x16_f16(pA.h8, vb1, o1, 0, 0, 0);
            }
        }
        __builtin_amdgcn_s_setprio(0);

        p ^= 1;
    }

    // ---- finalize ----
    __syncthreads();
    if (hi == 0) Fs[w][ql] = l_s;
#pragma unroll
    for (int r = 0; r < 16; ++r) {
        const int qp = (r & 3) + 8 * (r >> 2) + 4 * hi;
        const float inv = 1.0f / Fs[w][qp];
        const int qrow = q0 + w * 32 + qp;
        Op[(poff + qrow) * HDIM + ql]      = (_Float16)(o0[r] * inv);
        Op[(poff + qrow) * HDIM + 32 + ql] = (_Float16)(o1[r] * inv);
    }
    if (hi == 0) {
        const int qrow = q0 + w * 32 + ql;
        reinterpret_cast<float2*>(ml)[poff + qrow] = make_float2(m_s, l_s);
    }
}

// ---------------------------------------------------------------------------
// Merge the KVSPLIT normalized partials -> hd (f16, heads layout).
// ---------------------------------------------------------------------------
__global__ __launch_bounds__(256) void attn_merge(const _Float16* __restrict__ Op,
                                                  const float* __restrict__ ml,
                                                  _Float16* __restrict__ hd) {
    const int t  = threadIdx.x;
    const int q  = blockIdx.x * 64 + (t >> 2);
    const int d0 = (t & 3) * 16;
    const int h  = blockIdx.y;
    const int b  = blockIdx.z;

    size_t offs[KVSPLIT];
    float2 mls[KVSPLIT];
#pragma unroll
    for (int s = 0; s < KVSPLIT; ++s) {
        offs[s] = (((size_t)s * BATCH + b) * NHEADS + h) * SEQ + q;
        mls[s] = reinterpret_cast<const float2*>(ml)[offs[s]];
    }
    float m = mls[0].x;
#pragma unroll
    for (int s = 1; s < KVSPLIT; ++s) m = fmaxf(m, mls[s].x);
    float wgt[KVSPLIT];
    float wsum = 0.f;
#pragma unroll
    for (int s = 0; s < KVSPLIT; ++s) {
        wgt[s] = mls[s].y * exp2f(mls[s].x - m);
        wsum += wgt[s];
    }
    float inv = 1.0f / wsum;

    float o[16] = {};
#pragma unroll
    for (int s = 0; s < KVSPLIT; ++s) {
        const _Float16* pp = Op + offs[s] * HDIM + d0;
        half8 a = *reinterpret_cast<const half8*>(pp);
        half8 c = *reinterpret_cast<const half8*>(pp + 8);
        float wv = wgt[s] * inv;
#pragma unroll
        for (int i = 0; i < 8; ++i) {
            o[i]     += wv * (float)a[i];
            o[8 + i] += wv * (float)c[i];
        }
    }
    half8 o0, o1;
#pragma unroll
    for (int i = 0; i < 8; ++i) { o0[i] = (_Float16)o[i]; o1[i] = (_Float16)o[8 + i]; }
    _Float16* dst = hd + (size_t)(b * SEQ + q) * PROJ + h * HDIM + d0;
    *reinterpret_cast<half8*>(dst)     = o0;
    *reinterpret_cast<half8*>(dst + 8) = o1;
}

// ---------------------------------------------------------------------------
extern "C" void kernel_launch(void* const* d_in, const int* in_sizes, int n_in,
                              void* d_out, int out_size, void* d_ws, size_t ws_size,
                              hipStream_t stream) {
    const float* x  = (const float*)d_in[0];   // (BL, EMBED)
    const float* pW = (const float*)d_in[1];   // (EMBED, PROJ)
    const float* pb = (const float*)d_in[2];   // (PROJ)
    const float* Wq = (const float*)d_in[3];   // (PROJ, PROJ)
    const float* Wk = (const float*)d_in[4];
    const float* Wv = (const float*)d_in[5];
    const float* oW = (const float*)d_in[6];   // (PROJ, EMBED)
    float* out = (float*)d_out;                // (BL, EMBED) fp32

    _Float16* ws    = (_Float16*)d_ws;
    _Float16* p_h   = ws;                                  // BL x PROJ
    _Float16* qkv   = p_h + (size_t)BL * PROJ;             // BL x 1536
    _Float16* hd    = qkv + (size_t)BL * QKVN;             // BL x PROJ
    _Float16* pWt   = hd + (size_t)BL * PROJ;              // PROJ x EMBED
    _Float16* qkvWt = pWt + (size_t)PROJ * EMBED;          // 1536 x PROJ
    _Float16* oWt   = qkvWt + (size_t)QKVN * PROJ;         // EMBED x PROJ
    _Float16* vtb   = oWt + (size_t)EMBED * PROJ;          // B*H*HDIM x SEQ
    _Float16* Oph   = vtb + (size_t)BATCH * NHEADS * HDIM * SEQ;  // KVSPLIT*B*H*SEQ*HDIM f16
    float*    mlb   = (float*)(Oph + (size_t)KVSPLIT * BATCH * NHEADS * SEQ * HDIM);

    dim3 blk(256);

    // ---- fused weight prep (attn scale * log2e folded into Wq) ----
    trconv_all<<<dim3(448), blk, 0, stream>>>(pW, Wq, Wk, Wv, oW, pWt, qkvWt, oWt);

    // ---- p = relu(x @ pW + b), f16 out : 64x64 tiles, 1-D grid 512 ----
    gemm_mfma<64, 64, 1, 1, 0><<<dim3((PROJ / 64) * (BL / 64)), blk, 0, stream>>>(
        (const void*)x, pWt, pb, (void*)p_h, BL, PROJ, EMBED, PROJ / 64);

    // ---- fused q|k|v = p @ [Wq|Wk|Wv], f16 out : 128x128 tiles, 1-D grid 384 ----
    gemm_mfma<128, 128, 0, 0, 0><<<dim3((QKVN / 128) * (BL / 128)), blk, 0, stream>>>(
        (const void*)p_h, qkvWt, nullptr, (void*)qkv, BL, QKVN, PROJ, QKVN / 128);

    // ---- pre-transpose V per head ----
    trans_v<<<dim3(SEQ / 64, NHEADS, BATCH), blk, 0, stream>>>(qkv + 2 * PROJ, vtb);

    // ---- attention: split-KV partials (1-D grid, XCD-swizzled) + merge ----
    attn_part<<<dim3((SEQ / 128) * KVSPLIT * NHEADS * BATCH), blk, 0, stream>>>(
        qkv, qkv + PROJ, vtb, Oph, mlb);
    attn_merge<<<dim3(SEQ / 64, NHEADS, BATCH), blk, 0, stream>>>(Oph, mlb, hd);

    // ---- out = heads @ oW, fp32 out : 128x64 tiles, 1-D grid 512 ----
    gemm_mfma<128, 64, 0, 0, 1><<<dim3((EMBED / 64) * (BL / 128)), blk, 0, stream>>>(
        (const void*)hd, oWt, nullptr, (void*)out, BL, EMBED, PROJ, EMBED / 64);
}